// Round 11
// baseline (2764.458 us; speedup 1.0000x reference)
//
#include <hip/hip_runtime.h>

#define BB 64
#define TT 512
#define EE 512
#define RR 2048
#define CPW 32    // columns per scan workgroup
#define RPG 16    // rows (batch) per group
#define NWGS 256  // 4 groups x 64 col-WGs
#define FPAD 16   // flag padding: 16 u32 = 64 B/flag
#define SPIN_CAP (1 << 18)   // watchdog: fail fast instead of hanging

typedef _Float16 f16;
typedef f16 f16x8 __attribute__((ext_vector_type(8)));
typedef float f32x4 __attribute__((ext_vector_type(4)));

__device__ __forceinline__ void gload16(const void* g, void* l) {
  __builtin_amdgcn_global_load_lds(
      (const __attribute__((address_space(1))) void*)g,
      (__attribute__((address_space(3))) void*)l, 16, 0, 0);
}

__device__ __forceinline__ float fast_tanh(float v) {
  float e = __expf(2.0f * v);
  return 1.0f - 2.0f / (e + 1.0f);
}

// write-through device-coherent 2B store (R2-R10 proven)
__device__ __forceinline__ void storeS(f16* p, f16 h) {
  union { f16 h; unsigned short s; } u;
  u.h = h;
  __hip_atomic_store((unsigned short*)p, u.s, __ATOMIC_RELAXED, __HIP_MEMORY_SCOPE_AGENT);
}

__device__ __forceinline__ unsigned flag_ld(const unsigned* p) {
  return __hip_atomic_load(p, __ATOMIC_RELAXED, __HIP_MEMORY_SCOPE_AGENT);
}
__device__ __forceinline__ void flag_st(unsigned* p, unsigned v) {
  __hip_atomic_store(p, v, __ATOMIC_RELAXED, __HIP_MEMORY_SCOPE_AGENT);
}

// 8 sc0 (L1-bypass, L2-served) 16B loads, imm offsets 0..448 (R5-R10 proven)
__device__ __forceinline__ void issue8(f16x8* dst, unsigned voff, const f16* sbase) {
#pragma unroll
  for (int i = 0; i < 8; ++i)
    asm volatile("global_load_dwordx4 %0, %1, %2 offset:%c3 sc0"
                 : "=v"(dst[i]) : "v"(voff), "s"(sbase), "i"(64 * i) : "memory");
}

template <int N>
__device__ __forceinline__ void wait_vm() {
  asm volatile("s_waitcnt vmcnt(%c0)" :: "i"(N) : "memory");
  __builtin_amdgcn_sched_barrier(0);   // rule #18
}

// workers-only barrier via monotonic LDS counter (poller free-runs);
// caller handles vmcnt; this drains LDS writes then rendezvous
__device__ __forceinline__ void wbar(unsigned* cnt, unsigned target, int lane) {
  asm volatile("s_waitcnt lgkmcnt(0)" ::: "memory");
  __builtin_amdgcn_sched_barrier(0);
  if (lane == 0)
    __hip_atomic_fetch_add(cnt, 1u, __ATOMIC_RELAXED, __HIP_MEMORY_SCOPE_WORKGROUP);
  unsigned v;
  int gd = 0;
  do {
    v = __hip_atomic_load(cnt, __ATOMIC_RELAXED, __HIP_MEMORY_SCOPE_WORKGROUP);
  } while (v < target && ++gd < (1 << 22));
  __builtin_amdgcn_sched_barrier(0);
}

// ---------------- prep kernels ----------------

__global__ void prep_emb(const int* __restrict__ x, const float* __restrict__ ew,
                         f16* __restrict__ emb) {
  const int row = blockIdx.x;            // token index (b*T + t)
  const int tok = x[row];
  const float4* src = (const float4*)(ew + (size_t)tok * EE);
  f16* dst = emb + (size_t)row * EE;
  const int i = threadIdx.x;             // 128 threads, 4 f16 each
  float4 v = src[i];
  union { f16 h[4]; unsigned long long u; } p;
  p.h[0] = (f16)v.x; p.h[1] = (f16)v.y; p.h[2] = (f16)v.z; p.h[3] = (f16)v.w;
  ((unsigned long long*)dst)[i] = p.u;
}

__global__ void prep_winT(const float* __restrict__ Win, f16* __restrict__ WinT) {
  const int i = blockIdx.x * blockDim.x + threadIdx.x;  // over EE*RR
  if (i < EE * RR) {
    const int k = i / RR, n = i % RR;
    WinT[(size_t)n * EE + k] = (f16)Win[i];
  }
}

// ---------------- projection GEMM: U[t][b][n] = emb[b,t,:] @ Win[:,n] ----------------

__launch_bounds__(256, 1)
__global__ void proj_gemm(const f16* __restrict__ A, const f16* __restrict__ Bt,
                          float* __restrict__ U) {
  __shared__ f16 As[128 * 32];
  __shared__ f16 Bs[128 * 32];
  const int tid = threadIdx.x;
  const int wv = tid >> 6, l = tid & 63;
  const int m0 = blockIdx.x * 128, n0 = blockIdx.y * 128;
  const int wm = wv >> 1, wn = wv & 1;
  const int srow = tid >> 2, sc = tid & 3;
  const int r = l & 15, kb = l >> 4;
  f32x4 acc[4][4] = {};

  for (int k0 = 0; k0 < EE; k0 += 32) {
    __syncthreads();
#pragma unroll
    for (int q = 0; q < 2; ++q) {
      const int row = q * 64 + srow;
      const int cc = sc ^ (row & 3);
      gload16(A + (size_t)(m0 + row) * EE + k0 + cc * 8,
              (char*)As + q * 4096 + wv * 1024);
      gload16(Bt + (size_t)(n0 + row) * EE + k0 + cc * 8,
              (char*)Bs + q * 4096 + wv * 1024);
    }
    __syncthreads();
    f16x8 af[4], bf[4];
#pragma unroll
    for (int mi = 0; mi < 4; ++mi) {
      const int row = wm * 64 + mi * 16 + r;
      af[mi] = *(const f16x8*)&As[row * 32 + ((kb ^ (row & 3)) * 8)];
    }
#pragma unroll
    for (int ni = 0; ni < 4; ++ni) {
      const int row = wn * 64 + ni * 16 + r;
      bf[ni] = *(const f16x8*)&Bs[row * 32 + ((kb ^ (row & 3)) * 8)];
    }
#pragma unroll
    for (int mi = 0; mi < 4; ++mi)
#pragma unroll
      for (int ni = 0; ni < 4; ++ni)
        acc[mi][ni] = __builtin_amdgcn_mfma_f32_16x16x32_f16(af[mi], bf[ni], acc[mi][ni], 0, 0, 0);
  }
  const int rb = kb * 4;
#pragma unroll
  for (int mi = 0; mi < 4; ++mi)
#pragma unroll
    for (int ni = 0; ni < 4; ++ni)
#pragma unroll
      for (int j = 0; j < 4; ++j) {
        const int m = m0 + wm * 64 + mi * 16 + rb + j;   // token index (b*512 + t)
        const int n = n0 + wn * 64 + ni * 16 + r;
        const int b = m >> 9, t = m & 511;
        __builtin_nontemporal_store(acc[mi][ni][j], &U[(size_t)(t * BB + b) * RR + n]);
      }
}

// ---------------- the sequential reservoir scan ----------------
// R6 protocol (proven), re-plumbed to kill L3 poll contention:
// * ONE poller wave per WG (wave 8) polls the group's 64 flags (64 lanes),
//   handles the per-XCD fence/fflag exactly as R6, then releases workers via
//   an LDS word and immediately starts polling the NEXT step (free-running:
//   detection overlaps worker compute). Workers never issue L3 flag loads.
// * Workers rendezvous via LDS-counter barriers only (never with the poller).
// * U prefetched one step ahead (inline-asm nt load sequenced after issue8;
//   counted vmcnt keeps it off the critical path).
// Coherence story unchanged from R6 (passing 3 rounds): write-through S +
// sc0 A-loads + per-step per-XCD leader invalidate, flags through L3.

__launch_bounds__(576, 1)
__global__ void scan_kernel(const float* __restrict__ R, const float* __restrict__ U,
                            f16* __restrict__ S, unsigned* __restrict__ flg,
                            unsigned* __restrict__ fflag) {
  __shared__ __align__(16) char ldsbuf[CPW * RR * 2 + 16 * 1040];  // 128K Rt + reduce buf
  __shared__ unsigned wcnt, rel;
  f16* Rt = (f16*)ldsbuf;
  const char* RtB = (const char*)ldsbuf;

  const int wg = blockIdx.x;
  const int xcd = wg & 7;                        // blockIdx%8 == XCD heuristic
  const int grp = xcd >> 1;                      // group on XCD pair
  const int cw = ((wg >> 3) << 1) | (wg & 1);    // 0..63 within group
  const bool leader = (wg >> 3) == 0;            // one leader WG per XCD bucket
  const int nbase = cw * CPW;
  const int rbase = grp * RPG;
  const int tid = threadIdx.x;
  const int wv = tid >> 6, l = tid & 63;
  unsigned* gflags = flg + (size_t)grp * 64 * FPAD;
  unsigned* myflag = gflags + cw * FPAD;
  unsigned* myff = fflag + xcd * FPAD;

  if (tid == 0) { wcnt = 0u; rel = 1u; }

  // tau = 1: state_1 = tanh(u_0) on own 16x32 patch; publish early
  const int mm = tid >> 5, cc = tid & 31;        // row-in-group, col-in-slice
  if (tid < 512) {
    f16 h = (f16)fast_tanh(U[(size_t)(rbase + mm) * RR + nbase + cc]);
    storeS(&S[(size_t)(BB * RR) + (size_t)(rbase + mm) * RR + nbase + cc], h);
  }
  __syncthreads();                               // drains stores + LDS init
  if (tid == 0) flag_st(myflag, 1u);

  // R column slice -> LDS (chunked conflict-free layout), once
  if (tid < 512) {
    const int c = tid & 31, kst = tid >> 5;
    for (int k = kst; k < RR; k += 16) {
      const float v = R[(size_t)k * RR + nbase + c];
      const int idx = ((k >> 5) << 10) + ((c >> 4) << 9) +
                      (((c & 15) << 2) + ((k >> 3) & 3)) * 8 + (k & 7);
      Rt[idx] = (f16)v;
    }
  }
  __syncthreads();

  if (wv < 8) {
    // ---------------- worker waves (no L3 flag traffic at all) ----------------
    const int r = l & 15, kb = l >> 4;
    const int kblk = (wv + cw) & 7;          // k-rotation: de-hotspot A-loads
    const unsigned voffA = (unsigned)((((rbase + r) * RR) + (kblk << 8) + kb * 8) * 2);
    const int bb0 = (r * 4 + kb) * 16;       // byte within 1024B chunk row
    // reduce-read coords for this thread's output element (mm, cc)
    const int ntr = cc >> 4;
    const int lred = (cc & 15) | ((mm >> 2) << 4);
    const int jred = mm & 3;
    const unsigned ubase = (unsigned)(((rbase + mm) * RR + nbase + cc) * 4);

    f16x8 abuf[8];
    unsigned btgt = 0;

    // prefetch u for tau=2 (consumed at step 2's reduce)
    float ucur;
    asm volatile("global_load_dword %0, %1, %2 nt"
                 : "=v"(ucur) : "v"(ubase + (unsigned)(1 * BB * RR * 4)), "s"(U) : "memory");
    wait_vm<0>();

    for (int tau = 2; tau <= TT; ++tau) {
      const f16* sprev = S + (size_t)((tau - 1) & 1) * (BB * RR);
      f16* snext = S + (size_t)(tau & 1) * (BB * RR);

      // wait for poller's LDS release (cheap, per-CU)
      {
        unsigned v; int gd = 0;
        do {
          v = __hip_atomic_load(&rel, __ATOMIC_RELAXED, __HIP_MEMORY_SCOPE_WORKGROUP);
        } while (v < (unsigned)tau && ++gd < (1 << 22));
      }

      // 8 sc0 A-loads, then next-step U prefetch (sequenced after by asm order)
      issue8(abuf, voffA, sprev);
      float unxt;
      {
        const int tn = (tau < TT) ? tau : TT - 1;
        asm volatile("global_load_dword %0, %1, %2 nt"
                     : "=v"(unxt) : "v"(ubase + (unsigned)(tn * BB * RR * 4)), "s"(U) : "memory");
      }

      f32x4 acc0 = {0.f, 0.f, 0.f, 0.f}, acc1 = {0.f, 0.f, 0.f, 0.f};
#define KSTEP(ks)                                                              \
  {                                                                            \
    const int kc = (kblk << 3) + (ks);                                         \
    f16x8 b0 = *(const f16x8*)(RtB + kc * 2048 + bb0);                         \
    f16x8 b1 = *(const f16x8*)(RtB + kc * 2048 + 1024 + bb0);                  \
    acc0 = __builtin_amdgcn_mfma_f32_16x16x32_f16(abuf[ks], b0, acc0, 0, 0, 0);\
    acc1 = __builtin_amdgcn_mfma_f32_16x16x32_f16(abuf[ks], b1, acc1, 0, 0, 0);\
  }
      wait_vm<5>();                            // [A0..A7,unxt]: A0..A3 ready
      KSTEP(0) KSTEP(1) KSTEP(2) KSTEP(3)
      wait_vm<1>();                            // A4..A7 ready (unxt still out)
      KSTEP(4) KSTEP(5) KSTEP(6) KSTEP(7)
#undef KSTEP

      // partial accumulators -> LDS (padded per-wave copies), 8-way reduce
      {
        char* red = ldsbuf + CPW * RR * 2;
        *(f32x4*)(red + (wv * 2 + 0) * 1040 + l * 16) = acc0;
        *(f32x4*)(red + (wv * 2 + 1) * 1040 + l * 16) = acc1;
      }
      wbar(&wcnt, btgt += 8, l);               // workers-only barrier 1
      {
        const char* red = ldsbuf + CPW * RR * 2;
        float s = 0.f;
#pragma unroll
        for (int w = 0; w < 8; ++w)
          s += *(const float*)(red + (w * 2 + ntr) * 1040 + lred * 16 + jred * 4);
        storeS(&snext[(size_t)(rbase + mm) * RR + nbase + cc],
               (f16)fast_tanh(s + ucur));
      }
      wait_vm<0>();                            // stores at L3 (unxt long retired)
      wbar(&wcnt, btgt += 8, l);               // workers-only barrier 2
      if (tid == 0) flag_st(myflag, (unsigned)tau);
      ucur = unxt;
    }
  } else {
    // ---------------- free-running poller wave (wv == 8) ----------------
    const unsigned* pollp = &gflags[(size_t)l * FPAD];   // 64 lanes <- 64 flags
    // prologue fence: clears previous-replay L2 lines before step-2 reads
    if (leader) {
      __builtin_amdgcn_fence(__ATOMIC_ACQUIRE, "agent");
      if (l == 0) flag_st(myff, 2u);
    }
    for (int tau = 2; tau <= TT; ++tau) {
      const unsigned need = (unsigned)(tau - 1);
      // poll all 64 producers (single wave per WG -> 8x less L3 pressure)
      {
        unsigned fv = flag_ld(pollp);
        int gd = 0;
        while (!__all(fv >= need) && ++gd < SPIN_CAP) {
          __builtin_amdgcn_s_sleep(1);
          fv = flag_ld(pollp);
        }
      }
      if (leader) {
        if (tau > 2) {  // tau==2 covered by prologue fence
          __builtin_amdgcn_fence(__ATOMIC_ACQUIRE, "agent");
          if (l == 0) flag_st(myff, (unsigned)tau);
        }
      } else {
        unsigned ffv = flag_ld(myff);
        int gd = 0;
        while (ffv < (unsigned)tau && ++gd < SPIN_CAP) {
          __builtin_amdgcn_s_sleep(1);
          ffv = flag_ld(myff);
        }
      }
      // release workers for step tau; loop on to poll tau+1 during compute
      __hip_atomic_store(&rel, (unsigned)tau, __ATOMIC_RELAXED,
                         __HIP_MEMORY_SCOPE_WORKGROUP);
    }
  }
}

// ---------------- LayerNorm ----------------

__launch_bounds__(256, 1)
__global__ void ln_kernel(const f16* __restrict__ Sfin, const float* __restrict__ gamma,
                          const float* __restrict__ beta, float* __restrict__ out) {
  const int b = blockIdx.x;
  const int tid = threadIdx.x;
  const f16* row = Sfin + (size_t)b * RR;
  float vals[8];
  float lsum = 0.f, lsq = 0.f;
#pragma unroll
  for (int i = 0; i < 8; ++i) {
    float v = (float)row[tid + i * 256];
    vals[i] = v; lsum += v; lsq += v * v;
  }
#pragma unroll
  for (int off = 32; off >= 1; off >>= 1) {
    lsum += __shfl_xor(lsum, off);
    lsq  += __shfl_xor(lsq, off);
  }
  __shared__ float ps[4], pq[4];
  __shared__ float mu_s, rstd_s;
  const int wv = tid >> 6, l = tid & 63;
  if (l == 0) { ps[wv] = lsum; pq[wv] = lsq; }
  __syncthreads();
  if (tid == 0) {
    float s = 0.f, q = 0.f;
    for (int i = 0; i < 4; ++i) { s += ps[i]; q += pq[i]; }
    const float mu = s / RR;
    const float var = q / RR - mu * mu;
    mu_s = mu; rstd_s = rsqrtf(var + 1e-5f);
  }
  __syncthreads();
  const float mu = mu_s, rstd = rstd_s;
#pragma unroll
  for (int i = 0; i < 8; ++i) {
    const int idx = tid + i * 256;
    out[(size_t)b * RR + idx] = (vals[i] - mu) * rstd * gamma[idx] + beta[idx];
  }
}

// ---------------- launch ----------------

extern "C" void kernel_launch(void* const* d_in, const int* in_sizes, int n_in,
                              void* d_out, int out_size, void* d_ws, size_t ws_size,
                              hipStream_t stream) {
  const int*   x     = (const int*)d_in[0];
  const float* ew    = (const float*)d_in[1];
  const float* Rm    = (const float*)d_in[2];
  const float* Win   = (const float*)d_in[3];
  const float* gamma = (const float*)d_in[4];
  const float* beta  = (const float*)d_in[5];

  const size_t U_OFF   = 0;                           // fp32  512*64*2048*4
  const size_t EMB_OFF = 268435456;                   // fp16  32768*512*2
  const size_t WT_OFF  = EMB_OFF + 33554432;          // fp16  2048*512*2
  const size_t S_OFF   = WT_OFF + 2097152;            // fp16  2*64*2048*2
  const size_t FLG_OFF = S_OFF + 524288;              // u32   256 flags x 64B
  const size_t FF_OFF  = FLG_OFF + 16384;             // u32   8 x 64B
  const size_t NEED    = FF_OFF + 1024;
  if (ws_size < NEED) {
    hipMemsetAsync(d_out, 0, (size_t)out_size * 4, stream);
    return;
  }
  char* ws = (char*)d_ws;
  float*    Ubuf  = (float*)(ws + U_OFF);
  f16*      emb   = (f16*)(ws + EMB_OFF);
  f16*      WinT  = (f16*)(ws + WT_OFF);
  f16*      Sbuf  = (f16*)(ws + S_OFF);
  unsigned* flg   = (unsigned*)(ws + FLG_OFF);
  unsigned* fflag = (unsigned*)(ws + FF_OFF);

  hipMemsetAsync(flg, 0, 16384 + 1024, stream);   // group flags + fence flags
  prep_emb<<<BB * TT, 128, 0, stream>>>(x, ew, emb);
  prep_winT<<<(EE * RR) / 256, 256, 0, stream>>>(Win, WinT);
  proj_gemm<<<dim3((BB * TT) / 128, RR / 128), 256, 0, stream>>>(emb, WinT, Ubuf);
  scan_kernel<<<NWGS, 576, 0, stream>>>(Rm, Ubuf, Sbuf, flg, fflag);
  // state_512 lives at instance 512&1 == 0
  ln_kernel<<<BB, 256, 0, stream>>>(Sbuf, gamma, beta, (float*)d_out);
}

// Round 13
// 1932.914 us; speedup vs baseline: 1.4302x; 1.4302x over previous
//
#include <hip/hip_runtime.h>

#define BB 64
#define TT 512
#define EE 512
#define RR 2048
#define CPW 32    // columns per scan workgroup
#define RPG 16    // rows (batch) per group
#define NWGS 256  // 4 groups x 64 col-WGs
#define FPAD 16   // flag padding: 16 u32 = 64 B/flag
#define SLOTB (BB * RR * 4)      // one U time-slot in bytes
#define GRPB  (RPG * RR * 4)     // one group's row-range within a slot (128KB)
#define SPIN_CAP (1 << 20)       // watchdog: fail fast instead of hanging

typedef _Float16 f16;
typedef f16 f16x8 __attribute__((ext_vector_type(8)));
typedef float f32x4 __attribute__((ext_vector_type(4)));

__device__ __forceinline__ void gload16(const void* g, void* l) {
  __builtin_amdgcn_global_load_lds(
      (const __attribute__((address_space(1))) void*)g,
      (__attribute__((address_space(3))) void*)l, 16, 0, 0);
}

__device__ __forceinline__ float fast_tanh(float v) {
  float e = __expf(2.0f * v);
  return 1.0f - 2.0f / (e + 1.0f);
}

// write-through device-coherent 2B store (R2-R11 proven): lands at L3
__device__ __forceinline__ void storeS(f16* p, f16 h) {
  union { f16 h; unsigned short s; } u;
  u.h = h;
  __hip_atomic_store((unsigned short*)p, u.s, __ATOMIC_RELAXED, __HIP_MEMORY_SCOPE_AGENT);
}

__device__ __forceinline__ unsigned flag_ld(const unsigned* p) {
  return __hip_atomic_load(p, __ATOMIC_RELAXED, __HIP_MEMORY_SCOPE_AGENT);
}
__device__ __forceinline__ void flag_st(unsigned* p, unsigned v) {
  __hip_atomic_store(p, v, __ATOMIC_RELAXED, __HIP_MEMORY_SCOPE_AGENT);
}

// 8 PLAIN CACHED 16B loads (single-assignment addressing makes caching safe)
__device__ __forceinline__ void issue8(f16x8* dst, unsigned voff, const f16* sbase) {
#pragma unroll
  for (int i = 0; i < 8; ++i)
    asm volatile("global_load_dwordx4 %0, %1, %2 offset:%c3"
                 : "=v"(dst[i]) : "v"(voff), "s"(sbase), "i"(64 * i) : "memory");
}

// L1/L2-bypass 4B load (keeps U addresses out of all caches — required for
// the single-assignment argument, since U slots are later reused for S)
__device__ __forceinline__ float bypass_ldf(unsigned voff, const float* base) {
  float v;
  asm volatile("global_load_dword %0, %1, %2 sc0 sc1"
               : "=v"(v) : "v"(voff), "s"(base) : "memory");
  return v;
}

template <int N>
__device__ __forceinline__ void wait_vm() {
  asm volatile("s_waitcnt vmcnt(%c0)" :: "i"(N) : "memory");
  __builtin_amdgcn_sched_barrier(0);   // rule #18
}

// ---------------- prep kernels ----------------

__global__ void prep_emb(const int* __restrict__ x, const float* __restrict__ ew,
                         f16* __restrict__ emb) {
  const int row = blockIdx.x;            // token index (b*T + t)
  const int tok = x[row];
  const float4* src = (const float4*)(ew + (size_t)tok * EE);
  f16* dst = emb + (size_t)row * EE;
  const int i = threadIdx.x;             // 128 threads, 4 f16 each
  float4 v = src[i];
  union { f16 h[4]; unsigned long long u; } p;
  p.h[0] = (f16)v.x; p.h[1] = (f16)v.y; p.h[2] = (f16)v.z; p.h[3] = (f16)v.w;
  ((unsigned long long*)dst)[i] = p.u;
}

__global__ void prep_winT(const float* __restrict__ Win, f16* __restrict__ WinT) {
  const int i = blockIdx.x * blockDim.x + threadIdx.x;  // over EE*RR
  if (i < EE * RR) {
    const int k = i / RR, n = i % RR;
    WinT[(size_t)n * EE + k] = (f16)Win[i];
  }
}

// ---------------- projection GEMM: U[t][b][n] = emb[b,t,:] @ Win[:,n] ----------------

__launch_bounds__(256, 1)
__global__ void proj_gemm(const f16* __restrict__ A, const f16* __restrict__ Bt,
                          float* __restrict__ U) {
  __shared__ f16 As[128 * 32];
  __shared__ f16 Bs[128 * 32];
  const int tid = threadIdx.x;
  const int wv = tid >> 6, l = tid & 63;
  const int m0 = blockIdx.x * 128, n0 = blockIdx.y * 128;
  const int wm = wv >> 1, wn = wv & 1;
  const int srow = tid >> 2, sc = tid & 3;
  const int r = l & 15, kb = l >> 4;
  f32x4 acc[4][4] = {};

  for (int k0 = 0; k0 < EE; k0 += 32) {
    __syncthreads();
#pragma unroll
    for (int q = 0; q < 2; ++q) {
      const int row = q * 64 + srow;
      const int cc = sc ^ (row & 3);
      gload16(A + (size_t)(m0 + row) * EE + k0 + cc * 8,
              (char*)As + q * 4096 + wv * 1024);
      gload16(Bt + (size_t)(n0 + row) * EE + k0 + cc * 8,
              (char*)Bs + q * 4096 + wv * 1024);
    }
    __syncthreads();
    f16x8 af[4], bf[4];
#pragma unroll
    for (int mi = 0; mi < 4; ++mi) {
      const int row = wm * 64 + mi * 16 + r;
      af[mi] = *(const f16x8*)&As[row * 32 + ((kb ^ (row & 3)) * 8)];
    }
#pragma unroll
    for (int ni = 0; ni < 4; ++ni) {
      const int row = wn * 64 + ni * 16 + r;
      bf[ni] = *(const f16x8*)&Bs[row * 32 + ((kb ^ (row & 3)) * 8)];
    }
#pragma unroll
    for (int mi = 0; mi < 4; ++mi)
#pragma unroll
      for (int ni = 0; ni < 4; ++ni)
        acc[mi][ni] = __builtin_amdgcn_mfma_f32_16x16x32_f16(af[mi], bf[ni], acc[mi][ni], 0, 0, 0);
  }
  const int rb = kb * 4;
#pragma unroll
  for (int mi = 0; mi < 4; ++mi)
#pragma unroll
    for (int ni = 0; ni < 4; ++ni)
#pragma unroll
      for (int j = 0; j < 4; ++j) {
        const int m = m0 + wm * 64 + mi * 16 + rb + j;   // token index (b*512 + t)
        const int n = n0 + wn * 64 + ni * 16 + r;
        const int b = m >> 9, t = m & 511;
        __builtin_nontemporal_store(acc[mi][ni][j], &U[(size_t)(t * BB + b) * RR + n]);
      }
}

// ---------------- the sequential reservoir scan (single-assignment S, group-local) ----
// R6 protocol minus ALL per-step cache maintenance:
// * S_tau (tau>=2), group g's 16x2048 f16 slice, is stored (write-through,
//   lands at L3) into group g's OWN row-range of the U[tau-2] slot (128KB
//   region at byte rbase*RR*4; the 64KB f16 slice fits in its first half).
//   R12 bug fixed: no byte the writer touches belongs to another group.
// * Safety: the writer's pre-store barrier follows all 8 waves' octet polls
//   => all 64 group flags >= tau-1 => every group thread's bypass U[tau-2]
//   read retired (reads retire before the tau-1 flag publish). Same-group
//   readers A-load slot tau-2 only at step tau+1, after flags >= tau.
// * Slot cached-touch timeline: bypass U-read (never cached) -> write-through
//   S-write (L3) -> first-and-only cached A-read -> L2 miss -> fresh L3 data.
//   NO per-step fences or invalidates anywhere.
// * One prologue acquire fence per WG clears cross-launch L2 residue.
// * Flags: exactly R6. Summation order unchanged -> bit-identical numerics.

__launch_bounds__(512, 1)
__global__ void scan_kernel(const float* __restrict__ R, float* Ub /*aliases S-history*/,
                            f16* S1, unsigned* __restrict__ flg) {
  __shared__ __align__(16) char ldsbuf[CPW * RR * 2 + 16 * 1040];  // 128K Rt + reduce buf
  f16* Rt = (f16*)ldsbuf;
  const char* RtB = (const char*)ldsbuf;

  const int wg = blockIdx.x;
  const int xcd = wg & 7;                        // heuristic (perf only)
  const int grp = xcd >> 1;                      // group on XCD pair
  const int cw = ((wg >> 3) << 1) | (wg & 1);    // 0..63 within group
  const int nbase = cw * CPW;
  const int rbase = grp * RPG;
  const int tid = threadIdx.x;
  const int wv = tid >> 6, l = tid & 63;
  unsigned* gflags = flg + (size_t)grp * 64 * FPAD;
  unsigned* myflag = gflags + cw * FPAD;
  const size_t grpoff = (size_t)grp * GRPB;      // group's byte range in a slot

  // prologue: one-time L1/L2 invalidate (cross-launch residue)
  __builtin_amdgcn_fence(__ATOMIC_ACQUIRE, "agent");

  // tau = 1: state_1 = tanh(u_0) -> S1 (group-local layout [grp][16][RR])
  const int mm = tid >> 5, cc = tid & 31;        // row-in-group, col-in-slice
  {
    const unsigned u0off = (unsigned)((((rbase + mm) * RR) + nbase + cc) * 4);
    float u0 = bypass_ldf(u0off, Ub);
    wait_vm<0>();
    storeS(&S1[(size_t)grp * (RPG * RR) + mm * RR + nbase + cc], (f16)fast_tanh(u0));
  }
  __syncthreads();                               // drains stores
  if (tid == 0) flag_st(myflag, 1u);

  // R column slice -> LDS (chunked conflict-free layout), once
  {
    const int c = tid & 31, kst = tid >> 5;
    for (int k = kst; k < RR; k += 16) {
      const float v = R[(size_t)k * RR + nbase + c];
      const int idx = ((k >> 5) << 10) + ((c >> 4) << 9) +
                      (((c & 15) << 2) + ((k >> 3) & 3)) * 8 + (k & 7);
      Rt[idx] = (f16)v;
    }
  }
  __syncthreads();

  const int r = l & 15, kb = l >> 4;       // r = LOCAL row 0..15
  const int kblk = (wv + cw) & 7;          // k-rotation: de-hotspot + octet polls
  const unsigned voffA = (unsigned)(((r * RR) + (kblk << 8) + kb * 8) * 2);
  const int bb0 = (r * 4 + kb) * 16;       // byte within 1024B chunk row
  // reduce-read coords for this thread's output element (mm, cc)
  const int ntr = cc >> 4;
  const int lred = (cc & 15) | ((mm >> 2) << 4);
  const int jred = mm & 3;
  const unsigned ubyte = (unsigned)((((rbase + mm) * RR) + nbase + cc) * 4);

  f16x8 abuf[8];

  for (int tau = 2; tau <= TT; ++tau) {
    const unsigned need = (unsigned)(tau - 1);

    // per-wave poll of this wave's 8 producers (R6-proven shape)
    {
      const unsigned* pp = &gflags[(size_t)(kblk * 8 + (l & 7)) * FPAD];
      unsigned fv = flag_ld(pp);
      int gd = 0;
      while (!__all(fv >= need) && ++gd < SPIN_CAP) {
        __builtin_amdgcn_s_sleep(1);
        fv = flag_ld(pp);
      }
    }

    // S_{tau-1}: tau==2 -> S1 (group slice), else group slice of slot(tau-3)
    const f16* sprev = (tau == 2)
        ? (const f16*)(S1 + (size_t)grp * (RPG * RR))
        : (const f16*)((const char*)Ub + (size_t)(tau - 3) * SLOTB + grpoff);
    // S_tau destination: group slice of slot(tau-2)
    f16* snext = (f16*)((char*)Ub + (size_t)(tau - 2) * SLOTB + grpoff);

    // 8 plain cached A-loads, then the bypass U element (queue: A0..A7, U)
    issue8(abuf, voffA, sprev);
    float uval;
    asm volatile("global_load_dword %0, %1, %2 sc0 sc1"
                 : "=v"(uval)
                 : "v"(ubyte), "s"((const float*)((const char*)Ub + (size_t)(tau - 1) * SLOTB))
                 : "memory");

    f32x4 acc0 = {0.f, 0.f, 0.f, 0.f}, acc1 = {0.f, 0.f, 0.f, 0.f};
#define KSTEP(ks)                                                              \
  {                                                                            \
    const int kc = (kblk << 3) + (ks);                                         \
    f16x8 b0 = *(const f16x8*)(RtB + kc * 2048 + bb0);                         \
    f16x8 b1 = *(const f16x8*)(RtB + kc * 2048 + 1024 + bb0);                  \
    acc0 = __builtin_amdgcn_mfma_f32_16x16x32_f16(abuf[ks], b0, acc0, 0, 0, 0);\
    acc1 = __builtin_amdgcn_mfma_f32_16x16x32_f16(abuf[ks], b1, acc1, 0, 0, 0);\
  }
    wait_vm<5>();                            // A0..A3 ready (A4..7 + U out)
    KSTEP(0) KSTEP(1) KSTEP(2) KSTEP(3)
    wait_vm<1>();                            // A4..A7 ready (U out)
    KSTEP(4) KSTEP(5) KSTEP(6) KSTEP(7)
#undef KSTEP
    wait_vm<0>();                            // U ready

    // partial accumulators -> LDS (padded per-wave copies), 8-way reduce
    {
      char* red = ldsbuf + CPW * RR * 2;
      *(f32x4*)(red + (wv * 2 + 0) * 1040 + l * 16) = acc0;
      *(f32x4*)(red + (wv * 2 + 1) * 1040 + l * 16) = acc1;
    }
    __syncthreads();
    {
      const char* red = ldsbuf + CPW * RR * 2;
      float s = 0.f;
#pragma unroll
      for (int w = 0; w < 8; ++w)
        s += *(const float*)(red + (w * 2 + ntr) * 1040 + lred * 16 + jred * 4);
      storeS(&snext[(size_t)mm * RR + nbase + cc], (f16)fast_tanh(s + uval));
    }
    __syncthreads();                         // drains stores (vmcnt0 at barrier)
    if (tid == 0) flag_st(myflag, (unsigned)tau);
  }
}

// ---------------- LayerNorm (group-local final-state layout) ----------------

__launch_bounds__(256, 1)
__global__ void ln_kernel(const char* __restrict__ slotbase, const float* __restrict__ gamma,
                          const float* __restrict__ beta, float* __restrict__ out) {
  const int b = blockIdx.x;
  const int tid = threadIdx.x;
  const f16* row = (const f16*)(slotbase + (size_t)(b >> 4) * GRPB) + (size_t)(b & 15) * RR;
  float vals[8];
  float lsum = 0.f, lsq = 0.f;
#pragma unroll
  for (int i = 0; i < 8; ++i) {
    float v = (float)row[tid + i * 256];
    vals[i] = v; lsum += v; lsq += v * v;
  }
#pragma unroll
  for (int off = 32; off >= 1; off >>= 1) {
    lsum += __shfl_xor(lsum, off);
    lsq  += __shfl_xor(lsq, off);
  }
  __shared__ float ps[4], pq[4];
  __shared__ float mu_s, rstd_s;
  const int wv = tid >> 6, l = tid & 63;
  if (l == 0) { ps[wv] = lsum; pq[wv] = lsq; }
  __syncthreads();
  if (tid == 0) {
    float s = 0.f, q = 0.f;
    for (int i = 0; i < 4; ++i) { s += ps[i]; q += pq[i]; }
    const float mu = s / RR;
    const float var = q / RR - mu * mu;
    mu_s = mu; rstd_s = rsqrtf(var + 1e-5f);
  }
  __syncthreads();
  const float mu = mu_s, rstd = rstd_s;
#pragma unroll
  for (int i = 0; i < 8; ++i) {
    const int idx = tid + i * 256;
    out[(size_t)b * RR + idx] = (vals[i] - mu) * rstd * gamma[idx] + beta[idx];
  }
}

// ---------------- launch ----------------

extern "C" void kernel_launch(void* const* d_in, const int* in_sizes, int n_in,
                              void* d_out, int out_size, void* d_ws, size_t ws_size,
                              hipStream_t stream) {
  const int*   x     = (const int*)d_in[0];
  const float* ew    = (const float*)d_in[1];
  const float* Rm    = (const float*)d_in[2];
  const float* Win   = (const float*)d_in[3];
  const float* gamma = (const float*)d_in[4];
  const float* beta  = (const float*)d_in[5];

  const size_t U_OFF   = 0;                           // fp32  512*64*2048*4 (+S overlay)
  const size_t EMB_OFF = 268435456;                   // fp16  32768*512*2
  const size_t WT_OFF  = EMB_OFF + 33554432;          // fp16  2048*512*2
  const size_t S_OFF   = WT_OFF + 2097152;            // fp16  S_1 buffer (256KB used)
  const size_t FLG_OFF = S_OFF + 524288;              // u32   256 flags x 64B
  const size_t NEED    = FLG_OFF + 16384;
  if (ws_size < NEED) {
    hipMemsetAsync(d_out, 0, (size_t)out_size * 4, stream);
    return;
  }
  char* ws = (char*)d_ws;
  float*    Ubuf = (float*)(ws + U_OFF);
  f16*      emb  = (f16*)(ws + EMB_OFF);
  f16*      WinT = (f16*)(ws + WT_OFF);
  f16*      S1   = (f16*)(ws + S_OFF);
  unsigned* flg  = (unsigned*)(ws + FLG_OFF);

  hipMemsetAsync(flg, 0, 16384, stream);   // flags reset each launch (replay-safe)
  prep_emb<<<BB * TT, 128, 0, stream>>>(x, ew, emb);
  prep_winT<<<(EE * RR) / 256, 256, 0, stream>>>(Win, WinT);
  proj_gemm<<<dim3((BB * TT) / 128, RR / 128), 256, 0, stream>>>(emb, WinT, Ubuf);
  scan_kernel<<<NWGS, 512, 0, stream>>>(Rm, Ubuf, S1, flg);
  // S_512 lives in the group-local slices of slot U[510]
  ln_kernel<<<BB, 256, 0, stream>>>(ws + (size_t)(TT - 2) * SLOTB,
                                    gamma, beta, (float*)d_out);
}